// Round 7
// baseline (234.996 us; speedup 1.0000x reference)
//
#include <hip/hip_runtime.h>
#include <hip/hip_bf16.h>

// MHA block: x[4096,1024] fp32; Wq/Wk/Wv/Wo [1024,1024] fp32.
// R7: attention key-split 2x for occupancy. 512 blocks (2/CU, 2 waves/SIMD)
// couldn't hide exp/MFMA/barrier latency (Occupancy 20%, busy ~75%).
// Constant-shift softmax makes partials exactly combinable:
// O = (O0+O1)/(l0+l1). 1024 attn blocks (4/CU) write bf16 O^T partials +
// fp32 row-sums; attn_combine (512 blocks) sums, normalizes, transposes.

typedef __bf16 bf16_t;
typedef __bf16 bf16x8 __attribute__((ext_vector_type(8)));
typedef __bf16 bf16x4 __attribute__((ext_vector_type(4)));
typedef float f32x4 __attribute__((ext_vector_type(4)));

#define D_MODEL 1024
#define SEQ 4096
#define HEADS 16
#define DK 64
#define QSCALE 0.1803368801111204f  // log2(e)/8

// ---------------- casts fp32 -> bf16 ----------------
__global__ void cast_kernel(const float* __restrict__ in, bf16_t* __restrict__ out, int n) {
    int i = (blockIdx.x * blockDim.x + threadIdx.x) * 4;
    if (i < n) {
        float4 v = *(const float4*)(in + i);
        bf16x4 o;
        o[0] = (bf16_t)v.x; o[1] = (bf16_t)v.y; o[2] = (bf16_t)v.z; o[3] = (bf16_t)v.w;
        *(bf16x4*)(out + i) = o;
    }
}

__global__ void cast4_kernel(const float* __restrict__ a, const float* __restrict__ b,
                             const float* __restrict__ c, const float* __restrict__ d,
                             bf16_t* __restrict__ out) {
    int gi = blockIdx.x * blockDim.x + threadIdx.x;
    int which = gi >> 18;
    int i = (gi & 0x3FFFF) * 4;
    const float* src = which == 0 ? a : which == 1 ? b : which == 2 ? c : d;
    float4 v = *(const float4*)(src + i);
    bf16x4 o;
    o[0] = (bf16_t)v.x; o[1] = (bf16_t)v.y; o[2] = (bf16_t)v.z; o[3] = (bf16_t)v.w;
    *(bf16x4*)(out + (size_t)which * D_MODEL * D_MODEL + i) = o;
}

__device__ __forceinline__ void g2l16(const bf16_t* g, bf16_t* l) {
    __builtin_amdgcn_global_load_lds(
        (const __attribute__((address_space(1))) void*)g,
        (__attribute__((address_space(3))) void*)l, 16, 0, 0);
}

// ---------------- LDS-staged NT GEMM (unchanged) ----------------
template <int ROUTE>
__global__ __launch_bounds__(256, 4) void gemm_lds(const bf16_t* __restrict__ A,
                                                   const bf16_t* __restrict__ B,
                                                   void* __restrict__ out0,
                                                   void* __restrict__ out1,
                                                   void* __restrict__ out2,
                                                   int M, int N, int K) {
    __shared__ __align__(16) bf16_t As[128 * 64];
    __shared__ __align__(16) bf16_t Bs[64 * 64];

    const int tid = threadIdx.x;
    const int lane = tid & 63;
    const int wave = tid >> 6;
    const int l15 = lane & 15;
    const int lg  = lane >> 4;
    const int m0 = blockIdx.y * 128;
    const int n0 = blockIdx.x * 64;
    const int wm = (wave >> 1) * 64;
    const int wn = (wave & 1) * 32;

    const bf16_t* aSrc[4]; bf16_t* aDst[4];
#pragma unroll
    for (int it = 0; it < 4; it++) {
        int c = it * 256 + tid;
        int row = c >> 3, cc = (c & 7) ^ (row & 7);
        aSrc[it] = A + (size_t)(m0 + row) * K + cc * 8;
        aDst[it] = As + c * 8;
    }
    const bf16_t* bSrc[2]; bf16_t* bDst[2];
#pragma unroll
    for (int it = 0; it < 2; it++) {
        int c = it * 256 + tid;
        int row = c >> 3, cc = (c & 7) ^ (row & 7);
        bSrc[it] = B + (size_t)(n0 + row) * K + cc * 8;
        bDst[it] = Bs + c * 8;
    }

    int aoff[2][4], boff[2][2];
#pragma unroll
    for (int kk = 0; kk < 2; kk++) {
#pragma unroll
        for (int i = 0; i < 4; i++) {
            int row = wm + i * 16 + l15;
            aoff[kk][i] = row * 64 + (((kk << 2) | lg) ^ (row & 7)) * 8;
        }
#pragma unroll
        for (int j = 0; j < 2; j++) {
            int row = wn + j * 16 + l15;
            boff[kk][j] = row * 64 + (((kk << 2) | lg) ^ (row & 7)) * 8;
        }
    }

    f32x4 acc[4][2];
#pragma unroll
    for (int i = 0; i < 4; i++)
#pragma unroll
        for (int j = 0; j < 2; j++) acc[i][j] = f32x4{0.f, 0.f, 0.f, 0.f};

    for (int k0 = 0; k0 < K; k0 += 64) {
#pragma unroll
        for (int it = 0; it < 4; it++) g2l16(aSrc[it] + k0, aDst[it]);
#pragma unroll
        for (int it = 0; it < 2; it++) g2l16(bSrc[it] + k0, bDst[it]);
        __syncthreads();

#pragma unroll
        for (int kk = 0; kk < 2; kk++) {
            bf16x8 af[4], bfm[2];
#pragma unroll
            for (int i = 0; i < 4; i++) af[i] = *(const bf16x8*)(As + aoff[kk][i]);
#pragma unroll
            for (int j = 0; j < 2; j++) bfm[j] = *(const bf16x8*)(Bs + boff[kk][j]);
#pragma unroll
            for (int i = 0; i < 4; i++)
#pragma unroll
                for (int j = 0; j < 2; j++)
                    acc[i][j] = __builtin_amdgcn_mfma_f32_16x16x32_bf16(af[i], bfm[j], acc[i][j], 0, 0, 0);
        }
        __syncthreads();
    }

    const int ng = n0 + wn;
    if (ROUTE == 0) {
        float* C = (float*)out0;
#pragma unroll
        for (int i = 0; i < 4; i++)
#pragma unroll
            for (int r = 0; r < 4; r++) {
                int m = m0 + wm + i * 16 + lg * 4 + r;
                float* crow = C + (size_t)m * N + ng;
#pragma unroll
                for (int j = 0; j < 2; j++) crow[j * 16 + l15] = acc[i][j][r];
            }
    } else {
        if (ng < 2048) {
            const bool isQ = (ng < 1024);
            const float sc = isQ ? QSCALE : 1.0f;
            bf16_t* dst = isQ ? (bf16_t*)out0 : (bf16_t*)out1;
            int nn = ng & 1023;
#pragma unroll
            for (int i = 0; i < 4; i++)
#pragma unroll
                for (int r = 0; r < 4; r++) {
                    int m = m0 + wm + i * 16 + lg * 4 + r;
                    bf16_t* crow = dst + (size_t)m * D_MODEL + nn;
#pragma unroll
                    for (int j = 0; j < 2; j++) crow[j * 16 + l15] = (bf16_t)(acc[i][j][r] * sc);
                }
        } else {
            bf16_t* Vt = (bf16_t*)out2;
#pragma unroll
            for (int i = 0; i < 4; i++)
#pragma unroll
                for (int j = 0; j < 2; j++) {
                    int vcol = ng - 2048 + j * 16 + l15;
                    int m = m0 + wm + i * 16 + lg * 4;
                    bf16x4 v4;
#pragma unroll
                    for (int r = 0; r < 4; r++) v4[r] = (bf16_t)acc[i][j][r];
                    *(bf16x4*)(Vt + (size_t)vcol * SEQ + m) = v4;
                }
        }
    }
}

// ---------------- attention main: key-split, writes partials ----------------
// grid 1024: bid[0:3]=head code (XCD-local), bit4=ks (key half), [5:9]=qblk.
__global__ __launch_bounds__(256) void attn_kernel(const bf16_t* __restrict__ Q,
                                                   const bf16_t* __restrict__ Km,
                                                   const bf16_t* __restrict__ Vt,
                                                   bf16_t* __restrict__ Opart,
                                                   float* __restrict__ Lpart) {
    const int tid = threadIdx.x;
    const int lane = tid & 63;
    const int wave = tid >> 6;
    const int l15 = lane & 15;
    const int lg  = lane >> 4;
    const int bid = blockIdx.x;
    const int h    = (bid & 7) * 2 + ((bid >> 3) & 1);
    const int ks   = (bid >> 4) & 1;
    const int qblk = bid >> 5;
    const int cid  = (bid & 15) | (qblk << 4);  // 0..511 (head,qblk) id
    const int q0 = qblk * 128;
    const int hoff = h * DK;

    __shared__ struct { __align__(16) bf16_t K[64 * 64]; __align__(16) bf16_t V[64 * 64]; } sm;

    bf16x8 qf[2][2];
#pragma unroll
    for (int t = 0; t < 2; t++)
#pragma unroll
        for (int c = 0; c < 2; c++)
            qf[t][c] = *(const bf16x8*)(Q + (size_t)(q0 + wave * 32 + t * 16 + l15) * D_MODEL
                                        + hoff + c * 32 + lg * 8);

    f32x4 oacc[2][4], lfrag[2];
#pragma unroll
    for (int t = 0; t < 2; t++) {
        lfrag[t] = f32x4{0.f, 0.f, 0.f, 0.f};
#pragma unroll
        for (int dt = 0; dt < 4; dt++) oacc[t][dt] = f32x4{0.f, 0.f, 0.f, 0.f};
    }

    bf16x8 ones8;
#pragma unroll
    for (int j = 0; j < 8; j++) ones8[j] = (bf16_t)1.0f;

    const bf16_t* kSrc[2]; const bf16_t* vSrc[2];
#pragma unroll
    for (int it = 0; it < 2; it++) {
        int c = it * 256 + tid;
        int row = c >> 3, dc = (c & 7) ^ (row & 7);
        kSrc[it] = Km + (size_t)row * D_MODEL + hoff + dc * 8;
        vSrc[it] = Vt + (size_t)(hoff + row) * SEQ + dc * 8;
    }

    int kOff[4][2], vOff[2][2][4];
#pragma unroll
    for (int kt = 0; kt < 4; kt++)
#pragma unroll
        for (int c = 0; c < 2; c++) {
            int row = kt * 16 + l15;
            kOff[kt][c] = row * 64 + (((c * 4 + lg) ^ (row & 7)) * 8);
        }
#pragma unroll
    for (int kp = 0; kp < 2; kp++)
#pragma unroll
        for (int hf = 0; hf < 2; hf++)
#pragma unroll
            for (int dt = 0; dt < 4; dt++) {
                int row = dt * 16 + l15;
                vOff[kp][hf][dt] = row * 64 + (((kp * 4 + hf * 2 + (lg >> 1)) ^ (row & 7)) * 8)
                                   + (lg & 1) * 4;
            }

    for (int s = ks * 32; s < ks * 32 + 32; s++) {
#pragma unroll
        for (int it = 0; it < 2; it++) {
            g2l16(kSrc[it] + (size_t)s * 64 * D_MODEL, sm.K + (it * 256 + tid) * 8);
            g2l16(vSrc[it] + s * 64,                   sm.V + (it * 256 + tid) * 8);
        }
        __syncthreads();

#pragma unroll
        for (int kp = 0; kp < 2; kp++) {
            f32x4 st[2][2];
#pragma unroll
            for (int sub = 0; sub < 2; sub++) {
                const int kt = kp * 2 + sub;
                const bf16x8 kf0 = *(const bf16x8*)(sm.K + kOff[kt][0]);
                const bf16x8 kf1 = *(const bf16x8*)(sm.K + kOff[kt][1]);
#pragma unroll
                for (int t = 0; t < 2; t++) {
                    f32x4 a = f32x4{0.f, 0.f, 0.f, 0.f};
                    a = __builtin_amdgcn_mfma_f32_16x16x32_bf16(kf0, qf[t][0], a, 0, 0, 0);
                    a = __builtin_amdgcn_mfma_f32_16x16x32_bf16(kf1, qf[t][1], a, 0, 0, 0);
                    st[t][sub] = a;
                }
            }

            bf16x8 pbig[2];
#pragma unroll
            for (int t = 0; t < 2; t++) {
#pragma unroll
                for (int r = 0; r < 4; r++) {
                    pbig[t][r]     = (bf16_t)__builtin_amdgcn_exp2f(st[t][0][r]);
                    pbig[t][r + 4] = (bf16_t)__builtin_amdgcn_exp2f(st[t][1][r]);
                }
            }

            lfrag[0] = __builtin_amdgcn_mfma_f32_16x16x32_bf16(ones8, pbig[0], lfrag[0], 0, 0, 0);
            lfrag[1] = __builtin_amdgcn_mfma_f32_16x16x32_bf16(ones8, pbig[1], lfrag[1], 0, 0, 0);

#pragma unroll
            for (int dt = 0; dt < 4; dt++) {
                const bf16x4 v0 = *(const bf16x4*)(sm.V + vOff[kp][0][dt]);
                const bf16x4 v1 = *(const bf16x4*)(sm.V + vOff[kp][1][dt]);
                bf16x8 vf;
#pragma unroll
                for (int j = 0; j < 4; j++) { vf[j] = v0[j]; vf[j + 4] = v1[j]; }
                oacc[0][dt] = __builtin_amdgcn_mfma_f32_16x16x32_bf16(vf, pbig[0], oacc[0][dt], 0, 0, 0);
                oacc[1][dt] = __builtin_amdgcn_mfma_f32_16x16x32_bf16(vf, pbig[1], oacc[1][dt], 0, 0, 0);
            }
        }
        __syncthreads();
    }

    // partial epilogue: bf16 O^T partials (un-normalized) + fp32 row sums
#pragma unroll
    for (int dt = 0; dt < 4; dt++) {
        bf16x8 pk;
#pragma unroll
        for (int r = 0; r < 4; r++) {
            pk[r]     = (bf16_t)oacc[0][dt][r];
            pk[r + 4] = (bf16_t)oacc[1][dt][r];
        }
        *(bf16x8*)(Opart + ((size_t)((ks * 512 + cid) * 4 + dt) * 256 + tid) * 8) = pk;
    }
    if (lg == 0) {
#pragma unroll
        for (int t = 0; t < 2; t++)
            Lpart[(ks * 512 + cid) * 128 + wave * 32 + t * 16 + l15] = lfrag[t][0];
    }
}

// ---------------- combine: sum partials, normalize, transpose, store ----------
__global__ __launch_bounds__(256) void attn_combine(const bf16_t* __restrict__ Opart,
                                                    const float* __restrict__ Lpart,
                                                    bf16_t* __restrict__ O) {
    __shared__ __align__(16) bf16_t Ot[128][72];
    const int tid = threadIdx.x;
    const int lane = tid & 63;
    const int wave = tid >> 6;
    const int l15 = lane & 15;
    const int lg  = lane >> 4;
    const int cid = blockIdx.x;
    const int h    = (cid & 7) * 2 + ((cid >> 3) & 1);
    const int qblk = cid >> 4;
    const int q0 = qblk * 128;
    const int hoff = h * DK;

    float inv[2];
#pragma unroll
    for (int t = 0; t < 2; t++) {
        int q = wave * 32 + t * 16 + l15;
        inv[t] = 1.f / (Lpart[cid * 128 + q] + Lpart[(512 + cid) * 128 + q]);
    }

#pragma unroll
    for (int dt = 0; dt < 4; dt++) {
        const bf16x8 a = *(const bf16x8*)(Opart + ((size_t)(cid * 4 + dt) * 256 + tid) * 8);
        const bf16x8 b = *(const bf16x8*)(Opart + ((size_t)((512 + cid) * 4 + dt) * 256 + tid) * 8);
#pragma unroll
        for (int r = 0; r < 4; r++) {
            float v0 = (float)a[r] + (float)b[r];
            float v1 = (float)a[r + 4] + (float)b[r + 4];
            Ot[wave * 32 + l15][dt * 16 + lg * 4 + r]      = (bf16_t)(v0 * inv[0]);
            Ot[wave * 32 + 16 + l15][dt * 16 + lg * 4 + r] = (bf16_t)(v1 * inv[1]);
        }
    }
    __syncthreads();

    const int row = tid >> 1;
    const int half = tid & 1;
    bf16_t* orow = O + (size_t)(q0 + row) * D_MODEL + hoff + half * 32;
#pragma unroll
    for (int m = 0; m < 4; m++)
        *(bf16x8*)(orow + m * 8) = *(const bf16x8*)(&Ot[row][half * 32 + m * 8]);
}

// ---------------- launcher ----------------
extern "C" void kernel_launch(void* const* d_in, const int* in_sizes, int n_in,
                              void* d_out, int out_size, void* d_ws, size_t ws_size,
                              hipStream_t stream) {
    const float* x  = (const float*)d_in[0];
    const float* Wq = (const float*)d_in[1];
    const float* Wk = (const float*)d_in[2];
    const float* Wv = (const float*)d_in[3];
    const float* Wo = (const float*)d_in[4];
    float* out = (float*)d_out;

    char* ws = (char*)d_ws;
    bf16_t* xb    = (bf16_t*)(ws);               // 8 MB; dead after QKV GEMM
    bf16_t* Ab    = (bf16_t*)(ws);               // aliases xb (combine writes after)
    bf16_t* wqb   = (bf16_t*)(ws + (8u  << 20)); // weights 8-16 MB
    bf16_t* wob   = (bf16_t*)(ws + (14u << 20));
    bf16_t* Qb    = (bf16_t*)(ws + (16u << 20));
    bf16_t* Kb    = (bf16_t*)(ws + (24u << 20));
    bf16_t* Vtb   = (bf16_t*)(ws + (32u << 20));
    bf16_t* Opart = (bf16_t*)(ws + (40u << 20)); // 16 MB bf16 partials
    float*  Lpart = (float*) (ws + (56u << 20)); // 512 KB row sums

    const int nX = SEQ * D_MODEL;
    cast_kernel<<<nX / 4 / 256, 256, 0, stream>>>(x, xb, nX);
    cast4_kernel<<<4 * 1024, 256, 0, stream>>>(Wq, Wk, Wv, Wo, wqb);

    gemm_lds<1><<<dim3(3 * D_MODEL / 64, SEQ / 128), 256, 0, stream>>>(
        xb, wqb, Qb, Kb, Vtb, SEQ, 3 * D_MODEL, D_MODEL);

    attn_kernel<<<1024, 256, 0, stream>>>(Qb, Kb, Vtb, Opart, Lpart);
    attn_combine<<<512, 256, 0, stream>>>(Opart, Lpart, Ab);

    gemm_lds<0><<<dim3(D_MODEL / 64, SEQ / 128), 256, 0, stream>>>(
        Ab, wob, out, nullptr, nullptr, SEQ, D_MODEL, D_MODEL);
}

// Round 8
// 232.079 us; speedup vs baseline: 1.0126x; 1.0126x over previous
//
#include <hip/hip_runtime.h>
#include <hip/hip_bf16.h>

// MHA block: x[4096,1024] fp32; Wq/Wk/Wv/Wo [1024,1024] fp32.
// R8: key-split reverted (R7 post-mortem: combine cost > split gain).
// QKV GEMM upgraded to the m97-verified 128x128 tile (4 waves x 64x64,
// 4x4 acc/wave, BK=64, global_load_lds(16B), xor-swizzled LDS). Casts merged
// into one launch. Attention = R6 structure (S^T trick, exp2, K=32 PV).

typedef __bf16 bf16_t;
typedef __bf16 bf16x8 __attribute__((ext_vector_type(8)));
typedef __bf16 bf16x4 __attribute__((ext_vector_type(4)));
typedef float f32x4 __attribute__((ext_vector_type(4)));

#define D_MODEL 1024
#define SEQ 4096
#define HEADS 16
#define DK 64
#define QSCALE 0.1803368801111204f  // log2(e)/8

// ---------------- merged cast: x (4M) + 4 weights (4M) ----------------
__global__ void cast_all(const float* __restrict__ x,
                         const float* __restrict__ a, const float* __restrict__ b,
                         const float* __restrict__ c, const float* __restrict__ d,
                         bf16_t* __restrict__ xb, bf16_t* __restrict__ wb) {
    int gi = blockIdx.x * blockDim.x + threadIdx.x;  // 0..2M-1
    const float* src; bf16_t* dst; int i;
    if (gi < (1 << 20)) {
        i = gi * 4; src = x; dst = xb;
    } else {
        int g2 = gi - (1 << 20);
        int which = g2 >> 18;
        i = (g2 & 0x3FFFF) * 4;
        src = which == 0 ? a : which == 1 ? b : which == 2 ? c : d;
        dst = wb + (size_t)which * D_MODEL * D_MODEL;
    }
    float4 v = *(const float4*)(src + i);
    bf16x4 o;
    o[0] = (bf16_t)v.x; o[1] = (bf16_t)v.y; o[2] = (bf16_t)v.z; o[3] = (bf16_t)v.w;
    *(bf16x4*)(dst + i) = o;
}

__device__ __forceinline__ void g2l16(const bf16_t* g, bf16_t* l) {
    __builtin_amdgcn_global_load_lds(
        (const __attribute__((address_space(1))) void*)g,
        (__attribute__((address_space(3))) void*)l, 16, 0, 0);
}

// ---------------- 128x128 QKV GEMM (m97 structure) ----------------
// C[M,N]=A[M,K]B[N,K]^T, N=3072. Tile 128x128xBK64; 4 waves, each 64x64
// (4x4 16x16 tiles). Epilogue routes: bx<8 -> Q*QSCALE, bx<16 -> K,
// else V^T (Ct[d][seq]).
__global__ __launch_bounds__(256) void gemm_qkv(const bf16_t* __restrict__ A,
                                                const bf16_t* __restrict__ B,
                                                bf16_t* __restrict__ Qo,
                                                bf16_t* __restrict__ Ko,
                                                bf16_t* __restrict__ Vt) {
    __shared__ __align__(16) bf16_t As[128 * 64];  // 16 KB
    __shared__ __align__(16) bf16_t Bs[128 * 64];  // 16 KB

    const int tid = threadIdx.x;
    const int lane = tid & 63;
    const int wave = tid >> 6;
    const int l15 = lane & 15;
    const int lg  = lane >> 4;
    const int m0 = blockIdx.y * 128;
    const int n0 = blockIdx.x * 128;
    const int wm = (wave >> 1) * 64;
    const int wn = (wave & 1) * 64;
    const int K = D_MODEL;

    const bf16_t* aSrc[4]; bf16_t* aDst[4];
    const bf16_t* bSrc[4]; bf16_t* bDst[4];
#pragma unroll
    for (int it = 0; it < 4; it++) {
        int c = it * 256 + tid;
        int row = c >> 3, cc = (c & 7) ^ (row & 7);
        aSrc[it] = A + (size_t)(m0 + row) * K + cc * 8;
        aDst[it] = As + c * 8;
        bSrc[it] = B + (size_t)(n0 + row) * K + cc * 8;
        bDst[it] = Bs + c * 8;
    }

    int aoff[2][4], boff[2][4];
#pragma unroll
    for (int kk = 0; kk < 2; kk++)
#pragma unroll
        for (int i = 0; i < 4; i++) {
            int ra = wm + i * 16 + l15;
            aoff[kk][i] = ra * 64 + (((kk * 4 + lg) ^ (ra & 7)) * 8);
            int rb = wn + i * 16 + l15;
            boff[kk][i] = rb * 64 + (((kk * 4 + lg) ^ (rb & 7)) * 8);
        }

    f32x4 acc[4][4];
#pragma unroll
    for (int i = 0; i < 4; i++)
#pragma unroll
        for (int j = 0; j < 4; j++) acc[i][j] = f32x4{0.f, 0.f, 0.f, 0.f};

    for (int k0 = 0; k0 < K; k0 += 64) {
#pragma unroll
        for (int it = 0; it < 4; it++) {
            g2l16(aSrc[it] + k0, aDst[it]);
            g2l16(bSrc[it] + k0, bDst[it]);
        }
        __syncthreads();

#pragma unroll
        for (int kk = 0; kk < 2; kk++) {
            bf16x8 af[4], bfm[4];
#pragma unroll
            for (int i = 0; i < 4; i++) af[i] = *(const bf16x8*)(As + aoff[kk][i]);
#pragma unroll
            for (int j = 0; j < 4; j++) bfm[j] = *(const bf16x8*)(Bs + boff[kk][j]);
#pragma unroll
            for (int i = 0; i < 4; i++)
#pragma unroll
                for (int j = 0; j < 4; j++)
                    acc[i][j] = __builtin_amdgcn_mfma_f32_16x16x32_bf16(af[i], bfm[j], acc[i][j], 0, 0, 0);
        }
        __syncthreads();
    }

    const int bx = blockIdx.x;
    if (bx < 16) {
        const bool isQ = (bx < 8);
        const float sc = isQ ? QSCALE : 1.0f;
        bf16_t* dst = isQ ? Qo : Ko;
        const int nn = (n0 & 1023) + wn;
#pragma unroll
        for (int i = 0; i < 4; i++)
#pragma unroll
            for (int r = 0; r < 4; r++) {
                int m = m0 + wm + i * 16 + lg * 4 + r;
                bf16_t* crow = dst + (size_t)m * D_MODEL + nn;
#pragma unroll
                for (int j = 0; j < 4; j++) crow[j * 16 + l15] = (bf16_t)(acc[i][j][r] * sc);
            }
    } else {
        const int nb = n0 - 2048 + wn;
#pragma unroll
        for (int i = 0; i < 4; i++)
#pragma unroll
            for (int j = 0; j < 4; j++) {
                int vcol = nb + j * 16 + l15;
                int m = m0 + wm + i * 16 + lg * 4;
                bf16x4 v4;
#pragma unroll
                for (int r = 0; r < 4; r++) v4[r] = (bf16_t)acc[i][j][r];
                *(bf16x4*)(Vt + (size_t)vcol * SEQ + m) = v4;
            }
    }
}

// ---------------- 128x64 GEMM for final projection (fp32 out) ----------------
__global__ __launch_bounds__(256, 4) void gemm_out(const bf16_t* __restrict__ A,
                                                   const bf16_t* __restrict__ B,
                                                   float* __restrict__ C,
                                                   int M, int N, int K) {
    __shared__ __align__(16) bf16_t As[128 * 64];
    __shared__ __align__(16) bf16_t Bs[64 * 64];

    const int tid = threadIdx.x;
    const int lane = tid & 63;
    const int wave = tid >> 6;
    const int l15 = lane & 15;
    const int lg  = lane >> 4;
    const int m0 = blockIdx.y * 128;
    const int n0 = blockIdx.x * 64;
    const int wm = (wave >> 1) * 64;
    const int wn = (wave & 1) * 32;

    const bf16_t* aSrc[4]; bf16_t* aDst[4];
#pragma unroll
    for (int it = 0; it < 4; it++) {
        int c = it * 256 + tid;
        int row = c >> 3, cc = (c & 7) ^ (row & 7);
        aSrc[it] = A + (size_t)(m0 + row) * K + cc * 8;
        aDst[it] = As + c * 8;
    }
    const bf16_t* bSrc[2]; bf16_t* bDst[2];
#pragma unroll
    for (int it = 0; it < 2; it++) {
        int c = it * 256 + tid;
        int row = c >> 3, cc = (c & 7) ^ (row & 7);
        bSrc[it] = B + (size_t)(n0 + row) * K + cc * 8;
        bDst[it] = Bs + c * 8;
    }

    int aoff[2][4], boff[2][2];
#pragma unroll
    for (int kk = 0; kk < 2; kk++) {
#pragma unroll
        for (int i = 0; i < 4; i++) {
            int row = wm + i * 16 + l15;
            aoff[kk][i] = row * 64 + (((kk << 2) | lg) ^ (row & 7)) * 8;
        }
#pragma unroll
        for (int j = 0; j < 2; j++) {
            int row = wn + j * 16 + l15;
            boff[kk][j] = row * 64 + (((kk << 2) | lg) ^ (row & 7)) * 8;
        }
    }

    f32x4 acc[4][2];
#pragma unroll
    for (int i = 0; i < 4; i++)
#pragma unroll
        for (int j = 0; j < 2; j++) acc[i][j] = f32x4{0.f, 0.f, 0.f, 0.f};

    for (int k0 = 0; k0 < K; k0 += 64) {
#pragma unroll
        for (int it = 0; it < 4; it++) g2l16(aSrc[it] + k0, aDst[it]);
#pragma unroll
        for (int it = 0; it < 2; it++) g2l16(bSrc[it] + k0, bDst[it]);
        __syncthreads();

#pragma unroll
        for (int kk = 0; kk < 2; kk++) {
            bf16x8 af[4], bfm[2];
#pragma unroll
            for (int i = 0; i < 4; i++) af[i] = *(const bf16x8*)(As + aoff[kk][i]);
#pragma unroll
            for (int j = 0; j < 2; j++) bfm[j] = *(const bf16x8*)(Bs + boff[kk][j]);
#pragma unroll
            for (int i = 0; i < 4; i++)
#pragma unroll
                for (int j = 0; j < 2; j++)
                    acc[i][j] = __builtin_amdgcn_mfma_f32_16x16x32_bf16(af[i], bfm[j], acc[i][j], 0, 0, 0);
        }
        __syncthreads();
    }

#pragma unroll
    for (int i = 0; i < 4; i++)
#pragma unroll
        for (int r = 0; r < 4; r++) {
            int m = m0 + wm + i * 16 + lg * 4 + r;
            float* crow = C + (size_t)m * N + n0 + wn;
#pragma unroll
            for (int j = 0; j < 2; j++) crow[j * 16 + l15] = acc[i][j][r];
        }
}

// ---------------- attention (R6): S^T trick, exp2, K=32 PV ----------------
__global__ __launch_bounds__(256) void attn_kernel(const bf16_t* __restrict__ Q,
                                                   const bf16_t* __restrict__ Km,
                                                   const bf16_t* __restrict__ Vt,
                                                   bf16_t* __restrict__ O) {
    const int tid = threadIdx.x;
    const int lane = tid & 63;
    const int wave = tid >> 6;
    const int l15 = lane & 15;
    const int lg  = lane >> 4;
    const int bid = blockIdx.x;
    const int h    = (bid & 7) * 2 + ((bid >> 3) & 1);
    const int qblk = bid >> 4;
    const int q0 = qblk * 128;
    const int hoff = h * DK;

    __shared__ union {
        struct { __align__(16) bf16_t K[64 * 64]; __align__(16) bf16_t V[64 * 64]; } kv;
        __align__(16) bf16_t Ot[128][72];
    } sm;

    bf16x8 qf[2][2];
#pragma unroll
    for (int t = 0; t < 2; t++)
#pragma unroll
        for (int c = 0; c < 2; c++)
            qf[t][c] = *(const bf16x8*)(Q + (size_t)(q0 + wave * 32 + t * 16 + l15) * D_MODEL
                                        + hoff + c * 32 + lg * 8);

    f32x4 oacc[2][4], lfrag[2];
#pragma unroll
    for (int t = 0; t < 2; t++) {
        lfrag[t] = f32x4{0.f, 0.f, 0.f, 0.f};
#pragma unroll
        for (int dt = 0; dt < 4; dt++) oacc[t][dt] = f32x4{0.f, 0.f, 0.f, 0.f};
    }

    bf16x8 ones8;
#pragma unroll
    for (int j = 0; j < 8; j++) ones8[j] = (bf16_t)1.0f;

    const bf16_t* kSrc[2]; const bf16_t* vSrc[2];
#pragma unroll
    for (int it = 0; it < 2; it++) {
        int c = it * 256 + tid;
        int row = c >> 3, dc = (c & 7) ^ (row & 7);
        kSrc[it] = Km + (size_t)row * D_MODEL + hoff + dc * 8;
        vSrc[it] = Vt + (size_t)(hoff + row) * SEQ + dc * 8;
    }

    int kOff[4][2], vOff[2][2][4];
#pragma unroll
    for (int kt = 0; kt < 4; kt++)
#pragma unroll
        for (int c = 0; c < 2; c++) {
            int row = kt * 16 + l15;
            kOff[kt][c] = row * 64 + (((c * 4 + lg) ^ (row & 7)) * 8);
        }
#pragma unroll
    for (int kp = 0; kp < 2; kp++)
#pragma unroll
        for (int hf = 0; hf < 2; hf++)
#pragma unroll
            for (int dt = 0; dt < 4; dt++) {
                int row = dt * 16 + l15;
                vOff[kp][hf][dt] = row * 64 + (((kp * 4 + hf * 2 + (lg >> 1)) ^ (row & 7)) * 8)
                                   + (lg & 1) * 4;
            }

    for (int s = 0; s < SEQ / 64; s++) {
#pragma unroll
        for (int it = 0; it < 2; it++) {
            g2l16(kSrc[it] + (size_t)s * 64 * D_MODEL, sm.kv.K + (it * 256 + tid) * 8);
            g2l16(vSrc[it] + s * 64,                   sm.kv.V + (it * 256 + tid) * 8);
        }
        __syncthreads();

#pragma unroll
        for (int kp = 0; kp < 2; kp++) {
            f32x4 st[2][2];
#pragma unroll
            for (int sub = 0; sub < 2; sub++) {
                const int kt = kp * 2 + sub;
                const bf16x8 kf0 = *(const bf16x8*)(sm.kv.K + kOff[kt][0]);
                const bf16x8 kf1 = *(const bf16x8*)(sm.kv.K + kOff[kt][1]);
#pragma unroll
                for (int t = 0; t < 2; t++) {
                    f32x4 a = f32x4{0.f, 0.f, 0.f, 0.f};
                    a = __builtin_amdgcn_mfma_f32_16x16x32_bf16(kf0, qf[t][0], a, 0, 0, 0);
                    a = __builtin_amdgcn_mfma_f32_16x16x32_bf16(kf1, qf[t][1], a, 0, 0, 0);
                    st[t][sub] = a;
                }
            }

            bf16x8 pbig[2];
#pragma unroll
            for (int t = 0; t < 2; t++)
#pragma unroll
                for (int r = 0; r < 4; r++) {
                    pbig[t][r]     = (bf16_t)__builtin_amdgcn_exp2f(st[t][0][r]);
                    pbig[t][r + 4] = (bf16_t)__builtin_amdgcn_exp2f(st[t][1][r]);
                }

            lfrag[0] = __builtin_amdgcn_mfma_f32_16x16x32_bf16(ones8, pbig[0], lfrag[0], 0, 0, 0);
            lfrag[1] = __builtin_amdgcn_mfma_f32_16x16x32_bf16(ones8, pbig[1], lfrag[1], 0, 0, 0);

#pragma unroll
            for (int dt = 0; dt < 4; dt++) {
                const bf16x4 v0 = *(const bf16x4*)(sm.kv.V + vOff[kp][0][dt]);
                const bf16x4 v1 = *(const bf16x4*)(sm.kv.V + vOff[kp][1][dt]);
                bf16x8 vf;
#pragma unroll
                for (int j = 0; j < 4; j++) { vf[j] = v0[j]; vf[j + 4] = v1[j]; }
                oacc[0][dt] = __builtin_amdgcn_mfma_f32_16x16x32_bf16(vf, pbig[0], oacc[0][dt], 0, 0, 0);
                oacc[1][dt] = __builtin_amdgcn_mfma_f32_16x16x32_bf16(vf, pbig[1], oacc[1][dt], 0, 0, 0);
            }
        }
        __syncthreads();
    }

#pragma unroll
    for (int t = 0; t < 2; t++) {
        float inv = 1.f / lfrag[t][0];
        const int qrow = wave * 32 + t * 16 + l15;
#pragma unroll
        for (int dt = 0; dt < 4; dt++)
#pragma unroll
            for (int r = 0; r < 4; r++)
                sm.Ot[qrow][dt * 16 + lg * 4 + r] = (bf16_t)(oacc[t][dt][r] * inv);
    }
    __syncthreads();

    {
        const int row = tid >> 1;
        const int half = tid & 1;
        bf16_t* orow = O + (size_t)(q0 + row) * D_MODEL + hoff + half * 32;
#pragma unroll
        for (int m = 0; m < 4; m++)
            *(bf16x8*)(orow + m * 8) = *(const bf16x8*)(&sm.Ot[row][half * 32 + m * 8]);
    }
}

// ---------------- launcher ----------------
extern "C" void kernel_launch(void* const* d_in, const int* in_sizes, int n_in,
                              void* d_out, int out_size, void* d_ws, size_t ws_size,
                              hipStream_t stream) {
    const float* x  = (const float*)d_in[0];
    const float* Wq = (const float*)d_in[1];
    const float* Wk = (const float*)d_in[2];
    const float* Wv = (const float*)d_in[3];
    const float* Wo = (const float*)d_in[4];
    float* out = (float*)d_out;

    char* ws = (char*)d_ws;
    bf16_t* xb  = (bf16_t*)(ws);               // 8 MB
    bf16_t* wqb = (bf16_t*)(ws + (8u  << 20)); // wq/wk/wv/wo contiguous, 8 MB
    bf16_t* wob = (bf16_t*)(ws + (14u << 20));
    bf16_t* Qb  = (bf16_t*)(ws + (16u << 20));
    bf16_t* Kb  = (bf16_t*)(ws + (24u << 20));
    bf16_t* Vtb = (bf16_t*)(ws + (32u << 20));
    bf16_t* Ab  = (bf16_t*)(ws + (40u << 20));

    cast_all<<<8192, 256, 0, stream>>>(x, Wq, Wk, Wv, Wo, xb, wqb);

    gemm_qkv<<<dim3(3 * D_MODEL / 128, SEQ / 128), 256, 0, stream>>>(
        xb, wqb, Qb, Kb, Vtb);

    attn_kernel<<<512, 256, 0, stream>>>(Qb, Kb, Vtb, Ab);

    gemm_out<<<dim3(D_MODEL / 64, SEQ / 128), 256, 0, stream>>>(
        Ab, wob, out, SEQ, D_MODEL, D_MODEL);
}